// Round 10
// baseline (144.568 us; speedup 1.0000x reference)
//
#include <hip/hip_runtime.h>

#define N 64
#define MARGIN 0.1f
#define WAVES_PER_BLOCK 4
#define NBLOCKS 2048

// closed form (verified R2..R9, absmax 0.0): row_loss = sum_e u_e*(q_e - p_e)
//   p_e = #{k: lab_k < lab_e},  u_e = sc_e - MARGIN*p_e,  q_e = #{k: u_k < u_e}
//
// R10: vcc-free compare accumulation. R1-R9's `q += (a<b)` forms serialize on
// the single vcc register (cmp->sel->add, ~8 cyc/elem with hazards). Replace
// with sign-bit arithmetic: (a<b) == signbit(a-b) for distinct values:
//   p += as_int(a - b) >> 31   // 0 or -1; v_sub + v_ashr + v_add, no vcc
// Four truly independent accumulator chains. Supply unchanged from R9:
// pass1 = SMEM s_load_dwordx4, pass2 = 32 elems LDS b128 + 32 elems readlane.
// Second kernel folded in via last-block-done (device-scope counter in ws).
__global__ __launch_bounds__(256) void mmrl_kernel(const float* __restrict__ scores,
                                                   const float* __restrict__ labels,
                                                   float* __restrict__ out,
                                                   float* __restrict__ partial,
                                                   unsigned* __restrict__ counter,
                                                   int rows) {
    __shared__ float ubuf[WAVES_PER_BLOCK][N];
    __shared__ float wsum[WAVES_PER_BLOCK];
    __shared__ int lastflag;

    const int lane = threadIdx.x & 63;
    const int w    = threadIdx.x >> 6;
    const int gwave = blockIdx.x * WAVES_PER_BLOCK + w;
    const int nwaves = NBLOCKS * WAVES_PER_BLOCK;

    float acc = 0.0f;

    for (int row = gwave; row < rows; row += nwaves) {
        const int base = __builtin_amdgcn_readfirstlane(row) * N;
        const float labv = labels[base + lane];
        const float scv  = scores[base + lane];

        // ---- pass 1: label rank p (SMEM float4 broadcasts; sign-bit counts) ----
        const float4* L4 = (const float4*)(labels + base);
        int p0 = 0, p1 = 0, p2 = 0, p3 = 0;        // accumulate 0 / -1
        #pragma unroll
        for (int kk = 0; kk < N / 4; ++kk) {
            const float4 a = L4[kk];
            p0 += __float_as_int(a.x - labv) >> 31;
            p1 += __float_as_int(a.y - labv) >> 31;
            p2 += __float_as_int(a.z - labv) >> 31;
            p3 += __float_as_int(a.w - labv) >> 31;
        }
        const int pv = -((p0 + p1) + (p2 + p3));

        const float u = fmaf(-MARGIN, (float)pv, scv);

        // ---- pass 2a: elems 0..31 via LDS uniform float4 broadcasts ----
        ubuf[w][lane] = u;
        asm volatile("s_waitcnt lgkmcnt(0)" ::: "memory");
        const float4* U4 = (const float4*)ubuf[w];
        int q0 = 0, q1 = 0, q2 = 0, q3 = 0;
        #pragma unroll
        for (int kk = 0; kk < 8; ++kk) {
            const float4 a = U4[kk];
            q0 += __float_as_int(a.x - u) >> 31;
            q1 += __float_as_int(a.y - u) >> 31;
            q2 += __float_as_int(a.z - u) >> 31;
            q3 += __float_as_int(a.w - u) >> 31;
        }

        // ---- pass 2b: elems 32..63 via v_readlane (VALU supply) ----
        const int ub = __float_as_int(u);
        #pragma unroll
        for (int e = 32; e < 64; e += 4) {
            const float x0 = __int_as_float(__builtin_amdgcn_readlane(ub, e));
            const float x1 = __int_as_float(__builtin_amdgcn_readlane(ub, e + 1));
            const float x2 = __int_as_float(__builtin_amdgcn_readlane(ub, e + 2));
            const float x3 = __int_as_float(__builtin_amdgcn_readlane(ub, e + 3));
            q0 += __float_as_int(x0 - u) >> 31;
            q1 += __float_as_int(x1 - u) >> 31;
            q2 += __float_as_int(x2 - u) >> 31;
            q3 += __float_as_int(x3 - u) >> 31;
        }
        const int qv = -((q0 + q1) + (q2 + q3));

        acc = fmaf(u, (float)(qv - pv), acc);
    }

    // ---- wave reduction ----
    #pragma unroll
    for (int off = 32; off > 0; off >>= 1)
        acc += __shfl_down(acc, off, 64);

    if (lane == 0) wsum[w] = acc;
    __syncthreads();

    // ---- block partial + last-block-done final reduction ----
    if (threadIdx.x == 0) {
        float s = 0.0f;
        #pragma unroll
        for (int i = 0; i < WAVES_PER_BLOCK; ++i) s += wsum[i];
        __hip_atomic_store(&partial[blockIdx.x], s,
                           __ATOMIC_RELEASE, __HIP_MEMORY_SCOPE_AGENT);
        const unsigned old = __hip_atomic_fetch_add(counter, 1u,
                           __ATOMIC_ACQ_REL, __HIP_MEMORY_SCOPE_AGENT);
        lastflag = (old == NBLOCKS - 1);
    }
    __syncthreads();

    if (lastflag) {
        float s = 0.0f;
        for (int i = threadIdx.x; i < NBLOCKS; i += 256)
            s += __hip_atomic_load(&partial[i],
                                   __ATOMIC_RELAXED, __HIP_MEMORY_SCOPE_AGENT);
        #pragma unroll
        for (int off = 32; off > 0; off >>= 1)
            s += __shfl_down(s, off, 64);
        if (lane == 0) wsum[w] = s;
        __syncthreads();
        if (threadIdx.x == 0) {
            float t = 0.0f;
            #pragma unroll
            for (int i = 0; i < WAVES_PER_BLOCK; ++i) t += wsum[i];
            out[0] = t * (1.0f / (float)rows);
        }
    }
}

extern "C" void kernel_launch(void* const* d_in, const int* in_sizes, int n_in,
                              void* d_out, int out_size, void* d_ws, size_t ws_size,
                              hipStream_t stream) {
    const float* scores = (const float*)d_in[0];
    const float* labels = (const float*)d_in[1];
    float* out = (float*)d_out;
    float* partial = (float*)d_ws;                       // 2048 floats
    unsigned* counter = (unsigned*)((char*)d_ws + NBLOCKS * sizeof(float));
    const int rows = in_sizes[0] / N;                    // 32768

    (void)hipMemsetAsync(counter, 0, sizeof(unsigned), stream);  // ws is poisoned
    mmrl_kernel<<<NBLOCKS, 256, 0, stream>>>(scores, labels, out, partial,
                                             counter, rows);
}

// Round 11
// 80.146 us; speedup vs baseline: 1.8038x; 1.8038x over previous
//
#include <hip/hip_runtime.h>

#define N 64
#define MARGIN 0.1f
#define WAVES_PER_BLOCK 4
#define NBLOCKS 2048

// closed form (verified R2..R10, absmax 0.0): row_loss = sum_e u_e*(q_e - p_e)
//   p_e = #{k: lab_k < lab_e},  u_e = sc_e - MARGIN*p_e,  q_e = #{k: u_k < u_e}
//
// R11 = R8 (best structure, 84.3 us: two kernels, plain partial stores, no
// device-scope fences -- R10 proved agent-scope release/acq per block costs
// ~60 us in cache writeback/invalidate) + R10's vcc-free sign-bit counting:
//   (a<b) == signbit(a-b) for distinct values
//   p += as_int(a-b) >> 31            // 0 or -1; v_sub+v_ashr+v_add, no vcc
// Four genuinely independent accumulator chains (the (a<b)?1:0 form
// serializes all chains through the single vcc register).
__global__ __launch_bounds__(256) void mmrl_partial(const float* __restrict__ scores,
                                                    const float* __restrict__ labels,
                                                    float* __restrict__ partial,
                                                    int rows) {
    __shared__ float ubuf[WAVES_PER_BLOCK][N];
    __shared__ float wsum[WAVES_PER_BLOCK];

    const int lane = threadIdx.x & 63;
    const int w    = threadIdx.x >> 6;
    const int gwave = blockIdx.x * WAVES_PER_BLOCK + w;
    const int nwaves = NBLOCKS * WAVES_PER_BLOCK;

    float acc = 0.0f;

    for (int row = gwave; row < rows; row += nwaves) {
        const int base = __builtin_amdgcn_readfirstlane(row) * N;
        const float labv = labels[base + lane];   // coalesced per-lane copy
        const float scv  = scores[base + lane];

        // ---- pass 1: label rank p (SMEM float4 broadcasts; sign-bit counts) ----
        const float4* L4 = (const float4*)(labels + base);
        int p0 = 0, p1 = 0, p2 = 0, p3 = 0;       // accumulate 0 / -1
        #pragma unroll
        for (int kk = 0; kk < N / 4; ++kk) {
            const float4 a = L4[kk];
            p0 += __float_as_int(a.x - labv) >> 31;
            p1 += __float_as_int(a.y - labv) >> 31;
            p2 += __float_as_int(a.z - labv) >> 31;
            p3 += __float_as_int(a.w - labv) >> 31;
        }
        const int pv = -((p0 + p1) + (p2 + p3));

        const float u = fmaf(-MARGIN, (float)pv, scv);

        // ---- pass 2: u rank q (LDS uniform float4 broadcasts; sign-bit counts) ----
        ubuf[w][lane] = u;
        asm volatile("s_waitcnt lgkmcnt(0)" ::: "memory");  // intra-wave LDS in-order
        const float4* U4 = (const float4*)ubuf[w];
        int q0 = 0, q1 = 0, q2 = 0, q3 = 0;
        #pragma unroll
        for (int kk = 0; kk < N / 4; ++kk) {
            const float4 a = U4[kk];
            q0 += __float_as_int(a.x - u) >> 31;
            q1 += __float_as_int(a.y - u) >> 31;
            q2 += __float_as_int(a.z - u) >> 31;
            q3 += __float_as_int(a.w - u) >> 31;
        }
        const int qv = -((q0 + q1) + (q2 + q3));

        acc = fmaf(u, (float)(qv - pv), acc);
    }

    // ---- wave reduction ----
    #pragma unroll
    for (int off = 32; off > 0; off >>= 1)
        acc += __shfl_down(acc, off, 64);

    if (lane == 0) wsum[w] = acc;
    __syncthreads();
    if (threadIdx.x == 0) {
        float s = 0.0f;
        #pragma unroll
        for (int i = 0; i < WAVES_PER_BLOCK; ++i) s += wsum[i];
        partial[blockIdx.x] = s;          // plain store, no atomic, no fence
    }
}

__global__ __launch_bounds__(256) void mmrl_reduce(const float* __restrict__ partial,
                                                   float* __restrict__ out,
                                                   int npartial, float inv_rows) {
    const int t = threadIdx.x;
    float s = 0.0f;
    for (int i = t; i < npartial; i += 256)
        s += partial[i];
    #pragma unroll
    for (int off = 32; off > 0; off >>= 1)
        s += __shfl_down(s, off, 64);
    __shared__ float wsum[4];
    if ((t & 63) == 0) wsum[t >> 6] = s;
    __syncthreads();
    if (t == 0)
        out[0] = (wsum[0] + wsum[1] + wsum[2] + wsum[3]) * inv_rows;
}

extern "C" void kernel_launch(void* const* d_in, const int* in_sizes, int n_in,
                              void* d_out, int out_size, void* d_ws, size_t ws_size,
                              hipStream_t stream) {
    const float* scores = (const float*)d_in[0];
    const float* labels = (const float*)d_in[1];
    float* out = (float*)d_out;
    float* partial = (float*)d_ws;        // 2048 floats = 8 KB << ws_size
    const int rows = in_sizes[0] / N;     // 32768

    mmrl_partial<<<NBLOCKS, 256, 0, stream>>>(scores, labels, partial, rows);
    mmrl_reduce<<<1, 256, 0, stream>>>(partial, out, NBLOCKS, 1.0f / (float)rows);
}